// Round 11
// baseline (182.010 us; speedup 1.0000x reference)
//
#include <hip/hip_runtime.h>
#include <hip/hip_bf16.h>

#define N_NODES 50000
#define N_EDGES 800000
#define TOT_E   (N_EDGES + N_NODES)   // edges + self loops = 850000
#define NEG_SLOPE 0.2f
#define NBKT 196         // buckets of 256 nodes: 196*256 = 50176 >= 50000
#define NPB 256          // nodes per bucket
#define BKT_CAP 6144     // max edges per bucket (mean 4352, sd ~64)
#define CHUNK 4096       // edges per block in CSR pass A
#define NCHUNK ((TOT_E + CHUNK - 1) / CHUNK)   // 208
#define GEMM_BLKS ((N_NODES + 63) / 64)        // 782

typedef __attribute__((ext_vector_type(8))) short bf16x8;
typedef __attribute__((ext_vector_type(4))) float f32x4;
typedef __attribute__((ext_vector_type(4))) unsigned int u32x4;

static __device__ __forceinline__ unsigned short f2bf(float f) {
    unsigned int u = __float_as_uint(f);
    unsigned int r = (u + 0x7FFFu + ((u >> 16) & 1u)) >> 16;   // RNE
    return (unsigned short)r;
}
static __device__ __forceinline__ float bf2f(unsigned short h) {
    return __uint_as_float(((unsigned int)h) << 16);
}
static __device__ __forceinline__ unsigned short f2h(float f) {
    _Float16 h = (_Float16)f;                                   // v_cvt_f16_f32 (RNE)
    return __builtin_bit_cast(unsigned short, h);
}
static __device__ __forceinline__ float h2f(unsigned short u) {
    return (float)__builtin_bit_cast(_Float16, u);
}

// ------------------------------------------------- shared-memory role union
struct SmemGemm { unsigned short lds_a[64][264]; };   // 33792 B (+8 pad rows)
struct SmemKA {
    int h[NBKT];
    int lbase[NBKT];
    int lcur[NBKT];
    int sc[256];
    unsigned stage[CHUNK];
};                                                     // ~19.8 KB

// ------------------------------------------------- CSR pass A (device body)
// LDS bucket counting-sort of a 4096-edge chunk; coalesced run dump into
// fixed-capacity bucket regions. packed u32: src|local_dst<<16|bucket<<24
static __device__ void kA_body(SmemKA* s, int blk, const int* __restrict__ srcp,
                               const int* __restrict__ dstp, int* __restrict__ bcount,
                               unsigned* __restrict__ ebuf) {
    int t = threadIdx.x;
    if (t < NBKT) s->h[t] = 0;
    __syncthreads();
    int base = blk * CHUNK;
    int nloc = min(CHUNK, TOT_E - base);
    for (int i = t; i < nloc; i += 256) {
        int e = base + i;
        int d = (e < N_EDGES) ? dstp[e] : (e - N_EDGES);
        atomicAdd(&s->h[d >> 8], 1);
    }
    __syncthreads();
    if (t < NBKT) s->lbase[t] = s->h[t] ? atomicAdd(&bcount[t], s->h[t]) : 0;
    s->sc[t] = (t < NBKT) ? s->h[t] : 0;
    __syncthreads();
    for (int off = 1; off < 256; off <<= 1) {
        int v = (t >= off) ? s->sc[t - off] : 0;
        __syncthreads();
        s->sc[t] += v;
        __syncthreads();
    }
    if (t < NBKT) s->lcur[t] = s->sc[t] - s->h[t];   // exclusive: run start
    __syncthreads();
    for (int i = t; i < nloc; i += 256) {
        int e = base + i;
        int d = (e < N_EDGES) ? dstp[e] : (e - N_EDGES);
        int sv = (e < N_EDGES) ? srcp[e] : (e - N_EDGES);
        int b = d >> 8;
        int p = atomicAdd(&s->lcur[b], 1);
        s->stage[p] = (unsigned)sv | ((unsigned)(d & 255) << 16) | ((unsigned)b << 24);
    }
    __syncthreads();
    for (int i = t; i < nloc; i += 256) {
        unsigned v = s->stage[i];
        int b = v >> 24;
        int pl = s->lbase[b] + (i - (s->lcur[b] - s->h[b]));
        if (pl < BKT_CAP) ebuf[(size_t)b * BKT_CAP + pl] = v & 0xFFFFFFu;
    }
}

// ------------------------------------------------- MFMA dual linear (device body)
template <bool F32IN>
static __device__ void gemm_body(SmemGemm* sg, int bid, const void* __restrict__ Ain,
                                 const unsigned short* __restrict__ Bp,
                                 unsigned short* __restrict__ outA,
                                 unsigned short* __restrict__ outB, int M) {
    int tid = threadIdx.x;
    int n0 = bid * 64;
    if (F32IN) {
        const float* X = (const float*)Ain;
#pragma unroll
        for (int r = 0; r < 8; ++r) {
            int c = r * 256 + tid;
            int row = c >> 5;
            int col4 = (c & 31) * 4;
            int gr = n0 + row;
            if (gr >= M) gr = M - 1;
            f32x4 v = __builtin_nontemporal_load((const f32x4*)&X[(size_t)gr * 128 + col4]);
            ushort4 hh, ll;
            unsigned short* hp = &hh.x;
            unsigned short* lp = &ll.x;
#pragma unroll
            for (int q = 0; q < 4; ++q) {
                unsigned short hv = f2bf(v[q]);
                hp[q] = hv;
                lp[q] = f2bf(v[q] - bf2f(hv));
            }
            *(ushort4*)&sg->lds_a[row][col4] = hh;
            *(ushort4*)&sg->lds_a[row][128 + col4] = ll;
        }
    } else {
        const unsigned short* Ap = (const unsigned short*)Ain;
#pragma unroll
        for (int r = 0; r < 8; ++r) {
            int c = r * 256 + tid;
            int row = c >> 5;
            int col = (c & 31) * 8;
            int gr = n0 + row;
            if (gr >= M) gr = M - 1;
            u32x4 v = __builtin_nontemporal_load((const u32x4*)&Ap[(size_t)gr * 256 + col]);
            *(u32x4*)&sg->lds_a[row][col] = v;
        }
    }
    __syncthreads();

    int w = tid >> 6, lane = tid & 63;
    int lrow = lane & 15, lhi = lane >> 4;
    f32x4 acc[4][4] = {};
    const bf16x8* Bf = (const bf16x8*)Bp;
#pragma unroll
    for (int ks = 0; ks < 8; ++ks) {
        bf16x8 bfr[4], afr[4];
#pragma unroll
        for (int ct = 0; ct < 4; ++ct)
            bfr[ct] = Bf[(ks * 16 + (w * 4 + ct)) * 64 + lane];
#pragma unroll
        for (int mt = 0; mt < 4; ++mt)
            afr[mt] = *(const bf16x8*)&sg->lds_a[mt * 16 + lrow][ks * 32 + lhi * 8];
#pragma unroll
        for (int mt = 0; mt < 4; ++mt)
#pragma unroll
            for (int ct = 0; ct < 4; ++ct)
                acc[mt][ct] = __builtin_amdgcn_mfma_f32_16x16x32_bf16(
                    afr[mt], bfr[ct], acc[mt][ct], 0, 0, 0);
    }
#pragma unroll
    for (int mt = 0; mt < 4; ++mt) {
        int row0 = n0 + mt * 16 + lhi * 4;
#pragma unroll
        for (int ct = 0; ct < 4; ++ct) {
            int col = w * 64 + ct * 16 + lrow;
            unsigned short* dst = (col < 128) ? outA : outB;   // wave-uniform
            int cc = col & 127;
#pragma unroll
            for (int reg = 0; reg < 4; ++reg) {
                int rg = row0 + reg;
                if (rg < M) dst[(size_t)rg * 128 + cc] = f2h(acc[mt][ct][reg]);
            }
        }
    }
}

// ------------------------------------------------- fused: GEMM layer1 + CSR pass A
__global__ __launch_bounds__(256) void k_fused1(const float* __restrict__ x,
                                                const unsigned short* __restrict__ Bp1,
                                                unsigned short* __restrict__ xl,
                                                unsigned short* __restrict__ xr,
                                                const int* __restrict__ srcp,
                                                const int* __restrict__ dstp,
                                                int* __restrict__ bcount,
                                                unsigned* __restrict__ ebuf) {
    __shared__ __align__(16) unsigned char smem[sizeof(SmemGemm)];
    if (blockIdx.x < GEMM_BLKS)
        gemm_body<true>((SmemGemm*)smem, blockIdx.x, x, Bp1, xl, xr, N_NODES);
    else
        kA_body((SmemKA*)smem, blockIdx.x - GEMM_BLKS, srcp, dstp, bcount, ebuf);
}

// ------------------------------------------------- layer-2 GEMM (standalone)
__global__ __launch_bounds__(256) void k_mfma_lin2(const unsigned short* __restrict__ Ap,
                                                   const unsigned short* __restrict__ Bp,
                                                   unsigned short* __restrict__ outA,
                                                   unsigned short* __restrict__ outB, int M) {
    __shared__ __align__(16) unsigned char smem[sizeof(SmemGemm)];
    gemm_body<false>((SmemGemm*)smem, blockIdx.x, Ap, Bp, outA, outB, M);
}

// ------------------------------------------------- CSR pass B + inline bucket scan
__global__ __launch_bounds__(256) void kBs(const unsigned* __restrict__ ebuf,
                                           const int* __restrict__ bcount,
                                           int* __restrict__ rowptr,
                                           int* __restrict__ esrc) {
    __shared__ int sall[256];
    __shared__ int h[NPB];
    __shared__ int sc[NPB];
    __shared__ int st2[BKT_CAP];
    int b = blockIdx.x, t = threadIdx.x;
    int own = (t < NBKT) ? bcount[t] : 0;
    sall[t] = own;
    __syncthreads();
    for (int off = 1; off < 256; off <<= 1) {
        int v = (t >= off) ? sall[t - off] : 0;
        __syncthreads();
        sall[t] += v;
        __syncthreads();
    }
    int gb = (b == 0) ? 0 : sall[b - 1];      // exclusive bucket base
    int cnt = min(bcount[b], BKT_CAP);
    const unsigned* eb = ebuf + (size_t)b * BKT_CAP;
    h[t] = 0;
    __syncthreads();
    for (int i = t; i < cnt; i += 256)
        atomicAdd(&h[(eb[i] >> 16) & 255], 1);
    __syncthreads();
    sc[t] = h[t];
    __syncthreads();
    for (int off = 1; off < 256; off <<= 1) {
        int v = (t >= off) ? sc[t - off] : 0;
        __syncthreads();
        sc[t] += v;
        __syncthreads();
    }
    h[t] = sc[t] - h[t];   // exclusive scan (scatter cursor)
    __syncthreads();
    int node0 = b << 8;
    if (node0 + t < N_NODES) rowptr[node0 + t] = gb + h[t];
    if (b == NBKT - 1 && t == 0) rowptr[N_NODES] = TOT_E;
    for (int i = t; i < cnt; i += 256) {
        unsigned v = eb[i];
        int p = atomicAdd(&h[(v >> 16) & 255], 1);
        st2[p] = (int)(v & 0xFFFFu);
    }
    __syncthreads();
    for (int i = t; i < cnt; i += 256) esrc[gb + i] = st2[i];
}

// ------------------------------------------------- weight pack (both layers) + bcount zero
__global__ void k_pack2(const float* __restrict__ Wl1, const float* __restrict__ Wr1,
                        const float* __restrict__ Wl2, const float* __restrict__ Wr2,
                        unsigned short* __restrict__ Bp1, unsigned short* __restrict__ Bp2,
                        int* __restrict__ bcount) {
    if (blockIdx.x == 0 && threadIdx.x < NBKT) bcount[threadIdx.x] = 0;
    int gidx = blockIdx.x * 256 + threadIdx.x;   // 131072 total
    int which = gidx >> 16;
    int idx = gidx & 65535;
    const float* Wa = which ? Wl2 : Wl1;
    const float* Wb = which ? Wr2 : Wr1;
    unsigned short* Bp = which ? Bp2 : Bp1;
    int j = idx & 7, lane = (idx >> 3) & 63, t = idx >> 9;
    int ks = t >> 4, ctg = t & 15;
    int k = (ks * 32 + (lane >> 4) * 8 + j) & 127;
    int n = ctg * 16 + (lane & 15);
    float v = (n < 128) ? Wa[k * 128 + n] : Wb[k * 128 + (n - 128)];
    Bp[idx] = f2bf(v);
}

// ------------------------------------------------- fused score+softmax+aggregate
// R9-proven structure: one wave per node; 16 lanes per edge slot, 4 slots/wave;
// branchless scalar online softmax; rows prefetched 2 batches ahead, indices 3.
// NT loads on the STREAMING operands (esrc, xr) so the random-gather xl table
// keeps L2; xl gathers stay cacheable.
template <int H, bool BF16OUT>
__global__ __launch_bounds__(256) void k_gat(const int* __restrict__ rowptr,
                                             const int* __restrict__ esrc,
                                             const unsigned short* __restrict__ xlh,
                                             const unsigned short* __restrict__ xrh,
                                             const float* __restrict__ att,
                                             const float* __restrict__ bias,
                                             float* __restrict__ out,
                                             unsigned short* __restrict__ outb) {
    int n = (blockIdx.x * 256 + threadIdx.x) >> 6;
    int lane = threadIdx.x & 63;
    if (n >= N_NODES) return;
    int start = rowptr[n], end = rowptr[n + 1];
    int grp = lane >> 4, sub = lane & 15;
    int c0 = sub * 8;

    float xr8[8], a8[8];
    {
        u32x4 u = __builtin_nontemporal_load((const u32x4*)&xrh[(size_t)n * 128 + c0]);
#pragma unroll
        for (int q = 0; q < 4; ++q) {
            xr8[2 * q]     = h2f((unsigned short)u[q]);
            xr8[2 * q + 1] = h2f((unsigned short)(u[q] >> 16));
        }
        float4 av0 = *(const float4*)&att[c0];
        float4 av1 = *(const float4*)&att[c0 + 4];
        a8[0] = av0.x; a8[1] = av0.y; a8[2] = av0.z; a8[3] = av0.w;
        a8[4] = av1.x; a8[5] = av1.y; a8[6] = av1.z; a8[7] = av1.w;
    }

    float m = -1e30f, den = 0.f;
    float acc[8] = {0.f, 0.f, 0.f, 0.f, 0.f, 0.f, 0.f, 0.f};

    // prologue: indices for batches 0,1,2; rows for batches 0,1
    int last = end - 1;
    auto cidx = [&](int e) {
        return __builtin_nontemporal_load(&esrc[(e < end) ? e : last]);
    };
    int sA = cidx(start + grp);
    int sB = cidx(start + 4 + grp);
    int sC = cidx(start + 8 + grp);
    u32x4 u0 = *(const u32x4*)&xlh[(size_t)sA * 128 + c0];
    u32x4 u1 = *(const u32x4*)&xlh[(size_t)sB * 128 + c0];

    for (int i = start; i < end; i += 4) {
        bool valid = (i + grp) < end;
        u32x4 uc = u0;
        u0 = u1;
        u1 = *(const u32x4*)&xlh[(size_t)sC * 128 + c0];   // row for batch b+2
        sC = cidx(i + 12 + grp);                            // index for batch b+3
        float c[8];
#pragma unroll
        for (int q = 0; q < 4; ++q) {
            c[2 * q]     = h2f((unsigned short)uc[q]);
            c[2 * q + 1] = h2f((unsigned short)(uc[q] >> 16));
        }
        float t = 0.f;
#pragma unroll
        for (int j = 0; j < 8; ++j) {
            float v = c[j] + xr8[j];
            v = fmaxf(v, NEG_SLOPE * v);
            t = fmaf(v, a8[j], t);
        }
        const int STEPS = (H == 2) ? 3 : 4;
#pragma unroll
        for (int k = 0; k < STEPS; ++k)
            t += __shfl_xor(t, 1 << k, 64);
        float sc = valid ? t : -1e38f;

        float mn = fmaxf(m, sc);
        float corr = __expf(m - mn);
        float p = __expf(sc - mn);
        m = mn;
        den = fmaf(den, corr, p);
#pragma unroll
        for (int j = 0; j < 8; ++j)
            acc[j] = fmaf(acc[j], corr, p * c[j]);
    }

    // merge the 4 edge-slot groups (xor 16, then 32)
#pragma unroll
    for (int off = 16; off <= 32; off <<= 1) {
        float mo = __shfl_xor(m, off, 64);
        float deno = __shfl_xor(den, off, 64);
        float ao[8];
#pragma unroll
        for (int j = 0; j < 8; ++j) ao[j] = __shfl_xor(acc[j], off, 64);
        float mn = fmaxf(m, mo);
        float c1 = __expf(m - mn);
        float c2 = __expf(mo - mn);
        m = mn;
        den = den * c1 + deno * c2;
#pragma unroll
        for (int j = 0; j < 8; ++j)
            acc[j] = fmaf(acc[j], c1, ao[j] * c2);
    }

    if (grp == 0) {
        float inv = 1.f / (den + 1e-16f);
        float o[8];
        float4 bv0 = *(const float4*)&bias[c0];
        float4 bv1 = *(const float4*)&bias[c0 + 4];
        float bb[8] = {bv0.x, bv0.y, bv0.z, bv0.w, bv1.x, bv1.y, bv1.z, bv1.w};
#pragma unroll
        for (int j = 0; j < 8; ++j) {
            float v = fmaf(acc[j], inv, bb[j]);
            o[j] = (v > 0.f) ? v : (__expf(v) - 1.f);   // ELU
        }
        if (BF16OUT) {
            u32x4 hv, lv;
#pragma unroll
            for (int q = 0; q < 4; ++q) {
                unsigned short h0 = f2bf(o[2 * q]), h1 = f2bf(o[2 * q + 1]);
                unsigned short l0 = f2bf(o[2 * q] - bf2f(h0));
                unsigned short l1 = f2bf(o[2 * q + 1] - bf2f(h1));
                hv[q] = (unsigned)h0 | ((unsigned)h1 << 16);
                lv[q] = (unsigned)l0 | ((unsigned)l1 << 16);
            }
            *(u32x4*)&outb[(size_t)n * 256 + c0] = hv;
            *(u32x4*)&outb[(size_t)n * 256 + 128 + c0] = lv;
        } else {
            *(float4*)&out[(size_t)n * 128 + c0] = make_float4(o[0], o[1], o[2], o[3]);
            *(float4*)&out[(size_t)n * 128 + c0 + 4] = make_float4(o[4], o[5], o[6], o[7]);
        }
    }
}

// ---------------------------------------------------------------- launch
extern "C" void kernel_launch(void* const* d_in, const int* in_sizes, int n_in,
                              void* d_out, int out_size, void* d_ws, size_t ws_size,
                              hipStream_t stream) {
    const float* x    = (const float*)d_in[0];
    const int*   ei   = (const int*)d_in[1];
    const float* Wl1  = (const float*)d_in[2];
    const float* Wr1  = (const float*)d_in[3];
    const float* att1 = (const float*)d_in[4];
    const float* b1   = (const float*)d_in[5];
    const float* Wl2  = (const float*)d_in[6];
    const float* Wr2  = (const float*)d_in[7];
    const float* att2 = (const float*)d_in[8];
    const float* b2   = (const float*)d_in[9];
    const int* srcp = ei;
    const int* dstp = ei + N_EDGES;

    char* ws = (char*)d_ws;
    size_t off = 0;
    auto alloc = [&](size_t bytes) {
        void* p = ws + off;
        off = (off + bytes + 255) & ~(size_t)255;
        return p;
    };
    int*      bcount  = (int*)alloc(NBKT * sizeof(int));
    unsigned* ebuf    = (unsigned*)alloc((size_t)NBKT * BKT_CAP * sizeof(unsigned));
    int*      rowptr  = (int*)alloc((N_NODES + 1) * sizeof(int));
    int*      esrc    = (int*)alloc((size_t)TOT_E * sizeof(int));
    unsigned short* xp  = (unsigned short*)alloc((size_t)N_NODES * 256 * sizeof(short));
    unsigned short* Bp1 = (unsigned short*)alloc(65536 * sizeof(short));
    unsigned short* Bp2 = (unsigned short*)alloc(65536 * sizeof(short));
    unsigned short* xl  = (unsigned short*)alloc((size_t)N_NODES * 128 * sizeof(short));
    unsigned short* xr  = (unsigned short*)alloc((size_t)N_NODES * 128 * sizeof(short));

    // 1) weight pack (both layers) + bcount zero-init
    k_pack2<<<512, 256, 0, stream>>>(Wl1, Wr1, Wl2, Wr2, Bp1, Bp2, bcount);

    // 2) fused: layer-1 GEMM (782 blocks) + CSR pass A (208 blocks) — independent
    k_fused1<<<GEMM_BLKS + NCHUNK, 256, 0, stream>>>(x, Bp1, xl, xr, srcp, dstp,
                                                     bcount, ebuf);

    // 3) CSR pass B (bucket scan inlined)
    kBs<<<NBKT, 256, 0, stream>>>(ebuf, bcount, rowptr, esrc);

    // 4) layer 1 attention (heads=2, C=64, concat) -> hi/lo bf16 for layer-2 GEMM
    k_gat<2, true><<<(N_NODES + 3) / 4, 256, 0, stream>>>(rowptr, esrc, xl, xr, att1, b1,
                                                          nullptr, xp);
    // 5) layer-2 GEMM
    k_mfma_lin2<<<GEMM_BLKS, 256, 0, stream>>>(xp, Bp2, xl, xr, N_NODES);

    // 6) layer 2 attention (heads=1, C=128, mean over 1 head = identity)
    k_gat<1, false><<<(N_NODES + 3) / 4, 256, 0, stream>>>(rowptr, esrc, xl, xr, att2, b2,
                                                           (float*)d_out, nullptr);
}

// Round 13
// 166.543 us; speedup vs baseline: 1.0929x; 1.0929x over previous
//
#include <hip/hip_runtime.h>
#include <hip/hip_bf16.h>

#define N_NODES 50000
#define N_EDGES 800000
#define TOT_E   (N_EDGES + N_NODES)   // edges + self loops = 850000
#define NEG_SLOPE 0.2f
#define NBKT 196         // buckets of 256 nodes: 196*256 = 50176 >= 50000
#define NPB 256          // nodes per bucket
#define BKT_CAP 6144     // max edges per bucket (mean 4352, sd ~64)
#define CHUNK 4096       // edges per block in CSR pass A
#define NCHUNK ((TOT_E + CHUNK - 1) / CHUNK)   // 208
#define GEMM_BLKS ((N_NODES + 63) / 64)        // 782

typedef __attribute__((ext_vector_type(8))) short bf16x8;
typedef __attribute__((ext_vector_type(4))) float f32x4;
typedef __attribute__((ext_vector_type(4))) unsigned int u32x4;

static __device__ __forceinline__ unsigned short f2bf(float f) {
    unsigned int u = __float_as_uint(f);
    unsigned int r = (u + 0x7FFFu + ((u >> 16) & 1u)) >> 16;   // RNE
    return (unsigned short)r;
}
static __device__ __forceinline__ float bf2f(unsigned short h) {
    return __uint_as_float(((unsigned int)h) << 16);
}
static __device__ __forceinline__ unsigned short f2h(float f) {
    _Float16 h = (_Float16)f;                                   // v_cvt_f16_f32 (RNE)
    return __builtin_bit_cast(unsigned short, h);
}
static __device__ __forceinline__ float h2f(unsigned short u) {
    return (float)__builtin_bit_cast(_Float16, u);
}

// ------------------------------------------------- shared-memory role union
struct SmemGemm { unsigned short lds_a[64][264]; };   // 33792 B (+8 pad rows)
struct SmemKA {
    int h[NBKT];
    int lbase[NBKT];
    int lcur[NBKT];
    int sc[256];
    unsigned stage[CHUNK];
};                                                     // ~19.8 KB

// ------------------------------------------------- CSR pass A (device body)
static __device__ void kA_body(SmemKA* s, int blk, const int* __restrict__ srcp,
                               const int* __restrict__ dstp, int* __restrict__ bcount,
                               unsigned* __restrict__ ebuf) {
    int t = threadIdx.x;
    if (t < NBKT) s->h[t] = 0;
    __syncthreads();
    int base = blk * CHUNK;
    int nloc = min(CHUNK, TOT_E - base);
    for (int i = t; i < nloc; i += 256) {
        int e = base + i;
        int d = (e < N_EDGES) ? dstp[e] : (e - N_EDGES);
        atomicAdd(&s->h[d >> 8], 1);
    }
    __syncthreads();
    if (t < NBKT) s->lbase[t] = s->h[t] ? atomicAdd(&bcount[t], s->h[t]) : 0;
    s->sc[t] = (t < NBKT) ? s->h[t] : 0;
    __syncthreads();
    for (int off = 1; off < 256; off <<= 1) {
        int v = (t >= off) ? s->sc[t - off] : 0;
        __syncthreads();
        s->sc[t] += v;
        __syncthreads();
    }
    if (t < NBKT) s->lcur[t] = s->sc[t] - s->h[t];   // exclusive: run start
    __syncthreads();
    for (int i = t; i < nloc; i += 256) {
        int e = base + i;
        int d = (e < N_EDGES) ? dstp[e] : (e - N_EDGES);
        int sv = (e < N_EDGES) ? srcp[e] : (e - N_EDGES);
        int b = d >> 8;
        int p = atomicAdd(&s->lcur[b], 1);
        s->stage[p] = (unsigned)sv | ((unsigned)(d & 255) << 16) | ((unsigned)b << 24);
    }
    __syncthreads();
    for (int i = t; i < nloc; i += 256) {
        unsigned v = s->stage[i];
        int b = v >> 24;
        int pl = s->lbase[b] + (i - (s->lcur[b] - s->h[b]));
        if (pl < BKT_CAP) ebuf[(size_t)b * BKT_CAP + pl] = v & 0xFFFFFFu;
    }
}

// ------------------------------------------------- MFMA dual linear (device body)
template <bool F32IN>
static __device__ void gemm_body(SmemGemm* sg, int bid, const void* __restrict__ Ain,
                                 const unsigned short* __restrict__ Bp,
                                 unsigned short* __restrict__ outA,
                                 unsigned short* __restrict__ outB, int M) {
    int tid = threadIdx.x;
    int n0 = bid * 64;
    if (F32IN) {
        const float* X = (const float*)Ain;
#pragma unroll
        for (int r = 0; r < 8; ++r) {
            int c = r * 256 + tid;
            int row = c >> 5;
            int col4 = (c & 31) * 4;
            int gr = n0 + row;
            if (gr >= M) gr = M - 1;
            float4 v = *(const float4*)&X[(size_t)gr * 128 + col4];
            float vv[4] = {v.x, v.y, v.z, v.w};
            ushort4 hh, ll;
            unsigned short* hp = &hh.x;
            unsigned short* lp = &ll.x;
#pragma unroll
            for (int q = 0; q < 4; ++q) {
                unsigned short hv = f2bf(vv[q]);
                hp[q] = hv;
                lp[q] = f2bf(vv[q] - bf2f(hv));
            }
            *(ushort4*)&sg->lds_a[row][col4] = hh;
            *(ushort4*)&sg->lds_a[row][128 + col4] = ll;
        }
    } else {
        const unsigned short* Ap = (const unsigned short*)Ain;
#pragma unroll
        for (int r = 0; r < 8; ++r) {
            int c = r * 256 + tid;
            int row = c >> 5;
            int col = (c & 31) * 8;
            int gr = n0 + row;
            if (gr >= M) gr = M - 1;
            float4 v = *(const float4*)&Ap[(size_t)gr * 256 + col];
            *(float4*)&sg->lds_a[row][col] = v;
        }
    }
    __syncthreads();

    int w = tid >> 6, lane = tid & 63;
    int lrow = lane & 15, lhi = lane >> 4;
    f32x4 acc[4][4] = {};
    const bf16x8* Bf = (const bf16x8*)Bp;
#pragma unroll
    for (int ks = 0; ks < 8; ++ks) {
        bf16x8 bfr[4], afr[4];
#pragma unroll
        for (int ct = 0; ct < 4; ++ct)
            bfr[ct] = Bf[(ks * 16 + (w * 4 + ct)) * 64 + lane];
#pragma unroll
        for (int mt = 0; mt < 4; ++mt)
            afr[mt] = *(const bf16x8*)&sg->lds_a[mt * 16 + lrow][ks * 32 + lhi * 8];
#pragma unroll
        for (int mt = 0; mt < 4; ++mt)
#pragma unroll
            for (int ct = 0; ct < 4; ++ct)
                acc[mt][ct] = __builtin_amdgcn_mfma_f32_16x16x32_bf16(
                    afr[mt], bfr[ct], acc[mt][ct], 0, 0, 0);
    }
#pragma unroll
    for (int mt = 0; mt < 4; ++mt) {
        int row0 = n0 + mt * 16 + lhi * 4;
#pragma unroll
        for (int ct = 0; ct < 4; ++ct) {
            int col = w * 64 + ct * 16 + lrow;
            unsigned short* dst = (col < 128) ? outA : outB;   // wave-uniform
            int cc = col & 127;
#pragma unroll
            for (int reg = 0; reg < 4; ++reg) {
                int rg = row0 + reg;
                if (rg < M) dst[(size_t)rg * 128 + cc] = f2h(acc[mt][ct][reg]);
            }
        }
    }
}

// ------------------------------------------------- fused: GEMM layer1 + CSR pass A
__global__ __launch_bounds__(256) void k_fused1(const float* __restrict__ x,
                                                const unsigned short* __restrict__ Bp1,
                                                unsigned short* __restrict__ xl,
                                                unsigned short* __restrict__ xr,
                                                const int* __restrict__ srcp,
                                                const int* __restrict__ dstp,
                                                int* __restrict__ bcount,
                                                unsigned* __restrict__ ebuf) {
    __shared__ __align__(16) unsigned char smem[sizeof(SmemGemm)];
    if (blockIdx.x < GEMM_BLKS)
        gemm_body<true>((SmemGemm*)smem, blockIdx.x, x, Bp1, xl, xr, N_NODES);
    else
        kA_body((SmemKA*)smem, blockIdx.x - GEMM_BLKS, srcp, dstp, bcount, ebuf);
}

// ------------------------------------------------- layer-2 GEMM (standalone)
__global__ __launch_bounds__(256) void k_mfma_lin2(const unsigned short* __restrict__ Ap,
                                                   const unsigned short* __restrict__ Bp,
                                                   unsigned short* __restrict__ outA,
                                                   unsigned short* __restrict__ outB, int M) {
    __shared__ __align__(16) unsigned char smem[sizeof(SmemGemm)];
    gemm_body<false>((SmemGemm*)smem, blockIdx.x, Ap, Bp, outA, outB, M);
}

// ------------------------------------------------- CSR pass B + inline bucket scan
__global__ __launch_bounds__(256) void kBs(const unsigned* __restrict__ ebuf,
                                           const int* __restrict__ bcount,
                                           int* __restrict__ rowptr,
                                           int* __restrict__ esrc) {
    __shared__ int sall[256];
    __shared__ int h[NPB];
    __shared__ int sc[NPB];
    __shared__ int st2[BKT_CAP];
    int b = blockIdx.x, t = threadIdx.x;
    int own = (t < NBKT) ? bcount[t] : 0;
    sall[t] = own;
    __syncthreads();
    for (int off = 1; off < 256; off <<= 1) {
        int v = (t >= off) ? sall[t - off] : 0;
        __syncthreads();
        sall[t] += v;
        __syncthreads();
    }
    int gb = (b == 0) ? 0 : sall[b - 1];      // exclusive bucket base
    int cnt = min(bcount[b], BKT_CAP);
    const unsigned* eb = ebuf + (size_t)b * BKT_CAP;
    h[t] = 0;
    __syncthreads();
    for (int i = t; i < cnt; i += 256)
        atomicAdd(&h[(eb[i] >> 16) & 255], 1);
    __syncthreads();
    sc[t] = h[t];
    __syncthreads();
    for (int off = 1; off < 256; off <<= 1) {
        int v = (t >= off) ? sc[t - off] : 0;
        __syncthreads();
        sc[t] += v;
        __syncthreads();
    }
    h[t] = sc[t] - h[t];   // exclusive scan (scatter cursor)
    __syncthreads();
    int node0 = b << 8;
    if (node0 + t < N_NODES) rowptr[node0 + t] = gb + h[t];
    if (b == NBKT - 1 && t == 0) rowptr[N_NODES] = TOT_E;
    for (int i = t; i < cnt; i += 256) {
        unsigned v = eb[i];
        int p = atomicAdd(&h[(v >> 16) & 255], 1);
        st2[p] = (int)(v & 0xFFFFu);
    }
    __syncthreads();
    for (int i = t; i < cnt; i += 256) esrc[gb + i] = st2[i];
}

// ------------------------------------------------- weight pack (both layers) + bcount zero
__global__ void k_pack2(const float* __restrict__ Wl1, const float* __restrict__ Wr1,
                        const float* __restrict__ Wl2, const float* __restrict__ Wr2,
                        unsigned short* __restrict__ Bp1, unsigned short* __restrict__ Bp2,
                        int* __restrict__ bcount) {
    if (blockIdx.x == 0 && threadIdx.x < NBKT) bcount[threadIdx.x] = 0;
    int gidx = blockIdx.x * 256 + threadIdx.x;   // 131072 total
    int which = gidx >> 16;
    int idx = gidx & 65535;
    const float* Wa = which ? Wl2 : Wl1;
    const float* Wb = which ? Wr2 : Wr1;
    unsigned short* Bp = which ? Bp2 : Bp1;
    int j = idx & 7, lane = (idx >> 3) & 63, t = idx >> 9;
    int ks = t >> 4, ctg = t & 15;
    int k = (ks * 32 + (lane >> 4) * 8 + j) & 127;
    int n = ctg * 16 + (lane & 15);
    float v = (n < 128) ? Wa[k * 128 + n] : Wb[k * 128 + (n - 128)];
    Bp[idx] = f2bf(v);
}

// ------------------------------------------------- fused score+softmax+aggregate
// R9-proven structure, exact revert: one wave per node; 16 lanes per edge
// slot, 4 slots/wave; plain loads; branchless scalar f32 online softmax;
// rows prefetched 2 batches ahead, indices 3 ahead.
template <int H, bool BF16OUT>
__global__ __launch_bounds__(256) void k_gat(const int* __restrict__ rowptr,
                                             const int* __restrict__ esrc,
                                             const unsigned short* __restrict__ xlh,
                                             const unsigned short* __restrict__ xrh,
                                             const float* __restrict__ att,
                                             const float* __restrict__ bias,
                                             float* __restrict__ out,
                                             unsigned short* __restrict__ outb) {
    int n = (blockIdx.x * 256 + threadIdx.x) >> 6;
    int lane = threadIdx.x & 63;
    if (n >= N_NODES) return;
    int start = rowptr[n], end = rowptr[n + 1];
    int grp = lane >> 4, sub = lane & 15;
    int c0 = sub * 8;

    float xr8[8], a8[8];
    {
        u32x4 u = *(const u32x4*)&xrh[(size_t)n * 128 + c0];
#pragma unroll
        for (int q = 0; q < 4; ++q) {
            xr8[2 * q]     = h2f((unsigned short)u[q]);
            xr8[2 * q + 1] = h2f((unsigned short)(u[q] >> 16));
        }
        float4 av0 = *(const float4*)&att[c0];
        float4 av1 = *(const float4*)&att[c0 + 4];
        a8[0] = av0.x; a8[1] = av0.y; a8[2] = av0.z; a8[3] = av0.w;
        a8[4] = av1.x; a8[5] = av1.y; a8[6] = av1.z; a8[7] = av1.w;
    }

    float m = -1e30f, den = 0.f;
    float acc[8] = {0.f, 0.f, 0.f, 0.f, 0.f, 0.f, 0.f, 0.f};

    // prologue: indices for batches 0,1,2; rows for batches 0,1
    int last = end - 1;
    auto cidx = [&](int e) { return esrc[(e < end) ? e : last]; };
    int sA = cidx(start + grp);
    int sB = cidx(start + 4 + grp);
    int sC = cidx(start + 8 + grp);
    u32x4 u0 = *(const u32x4*)&xlh[(size_t)sA * 128 + c0];
    u32x4 u1 = *(const u32x4*)&xlh[(size_t)sB * 128 + c0];

    for (int i = start; i < end; i += 4) {
        bool valid = (i + grp) < end;
        u32x4 uc = u0;
        u0 = u1;
        u1 = *(const u32x4*)&xlh[(size_t)sC * 128 + c0];   // row for batch b+2
        sC = cidx(i + 12 + grp);                            // index for batch b+3
        float c[8];
#pragma unroll
        for (int q = 0; q < 4; ++q) {
            c[2 * q]     = h2f((unsigned short)uc[q]);
            c[2 * q + 1] = h2f((unsigned short)(uc[q] >> 16));
        }
        float t = 0.f;
#pragma unroll
        for (int j = 0; j < 8; ++j) {
            float v = c[j] + xr8[j];
            v = fmaxf(v, NEG_SLOPE * v);
            t = fmaf(v, a8[j], t);
        }
        const int STEPS = (H == 2) ? 3 : 4;
#pragma unroll
        for (int k = 0; k < STEPS; ++k)
            t += __shfl_xor(t, 1 << k, 64);
        float sc = valid ? t : -1e38f;

        float mn = fmaxf(m, sc);
        float corr = __expf(m - mn);
        float p = __expf(sc - mn);
        m = mn;
        den = fmaf(den, corr, p);
#pragma unroll
        for (int j = 0; j < 8; ++j)
            acc[j] = fmaf(acc[j], corr, p * c[j]);
    }

    // merge the 4 edge-slot groups (xor 16, then 32)
#pragma unroll
    for (int off = 16; off <= 32; off <<= 1) {
        float mo = __shfl_xor(m, off, 64);
        float deno = __shfl_xor(den, off, 64);
        float ao[8];
#pragma unroll
        for (int j = 0; j < 8; ++j) ao[j] = __shfl_xor(acc[j], off, 64);
        float mn = fmaxf(m, mo);
        float c1 = __expf(m - mn);
        float c2 = __expf(mo - mn);
        m = mn;
        den = den * c1 + deno * c2;
#pragma unroll
        for (int j = 0; j < 8; ++j)
            acc[j] = fmaf(acc[j], c1, ao[j] * c2);
    }

    if (grp == 0) {
        float inv = 1.f / (den + 1e-16f);
        float o[8];
        float4 bv0 = *(const float4*)&bias[c0];
        float4 bv1 = *(const float4*)&bias[c0 + 4];
        float bb[8] = {bv0.x, bv0.y, bv0.z, bv0.w, bv1.x, bv1.y, bv1.z, bv1.w};
#pragma unroll
        for (int j = 0; j < 8; ++j) {
            float v = fmaf(acc[j], inv, bb[j]);
            o[j] = (v > 0.f) ? v : (__expf(v) - 1.f);   // ELU
        }
        if (BF16OUT) {
            u32x4 hv, lv;
#pragma unroll
            for (int q = 0; q < 4; ++q) {
                unsigned short h0 = f2bf(o[2 * q]), h1 = f2bf(o[2 * q + 1]);
                unsigned short l0 = f2bf(o[2 * q] - bf2f(h0));
                unsigned short l1 = f2bf(o[2 * q + 1] - bf2f(h1));
                hv[q] = (unsigned)h0 | ((unsigned)h1 << 16);
                lv[q] = (unsigned)l0 | ((unsigned)l1 << 16);
            }
            *(u32x4*)&outb[(size_t)n * 256 + c0] = hv;
            *(u32x4*)&outb[(size_t)n * 256 + 128 + c0] = lv;
        } else {
            *(float4*)&out[(size_t)n * 128 + c0] = make_float4(o[0], o[1], o[2], o[3]);
            *(float4*)&out[(size_t)n * 128 + c0 + 4] = make_float4(o[4], o[5], o[6], o[7]);
        }
    }
}

// ---------------------------------------------------------------- launch
extern "C" void kernel_launch(void* const* d_in, const int* in_sizes, int n_in,
                              void* d_out, int out_size, void* d_ws, size_t ws_size,
                              hipStream_t stream) {
    const float* x    = (const float*)d_in[0];
    const int*   ei   = (const int*)d_in[1];
    const float* Wl1  = (const float*)d_in[2];
    const float* Wr1  = (const float*)d_in[3];
    const float* att1 = (const float*)d_in[4];
    const float* b1   = (const float*)d_in[5];
    const float* Wl2  = (const float*)d_in[6];
    const float* Wr2  = (const float*)d_in[7];
    const float* att2 = (const float*)d_in[8];
    const float* b2   = (const float*)d_in[9];
    const int* srcp = ei;
    const int* dstp = ei + N_EDGES;

    char* ws = (char*)d_ws;
    size_t off = 0;
    auto alloc = [&](size_t bytes) {
        void* p = ws + off;
        off = (off + bytes + 255) & ~(size_t)255;
        return p;
    };
    int*      bcount  = (int*)alloc(NBKT * sizeof(int));
    unsigned* ebuf    = (unsigned*)alloc((size_t)NBKT * BKT_CAP * sizeof(unsigned));
    int*      rowptr  = (int*)alloc((N_NODES + 1) * sizeof(int));
    int*      esrc    = (int*)alloc((size_t)TOT_E * sizeof(int));
    unsigned short* xp  = (unsigned short*)alloc((size_t)N_NODES * 256 * sizeof(short));
    unsigned short* Bp1 = (unsigned short*)alloc(65536 * sizeof(short));
    unsigned short* Bp2 = (unsigned short*)alloc(65536 * sizeof(short));
    unsigned short* xl  = (unsigned short*)alloc((size_t)N_NODES * 128 * sizeof(short));
    unsigned short* xr  = (unsigned short*)alloc((size_t)N_NODES * 128 * sizeof(short));

    // 1) weight pack (both layers) + bcount zero-init
    k_pack2<<<512, 256, 0, stream>>>(Wl1, Wr1, Wl2, Wr2, Bp1, Bp2, bcount);

    // 2) fused: layer-1 GEMM (782 blocks) + CSR pass A (208 blocks) — independent
    k_fused1<<<GEMM_BLKS + NCHUNK, 256, 0, stream>>>(x, Bp1, xl, xr, srcp, dstp,
                                                     bcount, ebuf);

    // 3) CSR pass B (bucket scan inlined)
    kBs<<<NBKT, 256, 0, stream>>>(ebuf, bcount, rowptr, esrc);

    // 4) layer 1 attention (heads=2, C=64, concat) -> hi/lo bf16 for layer-2 GEMM
    k_gat<2, true><<<(N_NODES + 3) / 4, 256, 0, stream>>>(rowptr, esrc, xl, xr, att1, b1,
                                                          nullptr, xp);
    // 5) layer-2 GEMM
    k_mfma_lin2<<<GEMM_BLKS, 256, 0, stream>>>(xp, Bp2, xl, xr, N_NODES);

    // 6) layer 2 attention (heads=1, C=128, mean over 1 head = identity)
    k_gat<1, false><<<(N_NODES + 3) / 4, 256, 0, stream>>>(rowptr, esrc, xl, xr, att2, b2,
                                                           (float*)d_out, nullptr);
}